// Round 1
// baseline (1241.689 us; speedup 1.0000x reference)
//
#include <hip/hip_runtime.h>
#include <hip/hip_fp16.h>

#define T_TOK 4096
#define H_DIM 1024
#define I_DIM 4096
#define E_NUM 8
#define K_TOP 2
#define AUX_COEF 0.001f

#define BM 128
#define BN 64
#define BK 32
#define LDK (BK + 8)                         // pad LDS rows to 40 (80B, 16B-aligned)
#define PADROWS (T_TOK * K_TOP + E_NUM * BM) // 9216
#define MAXMB (T_TOK * K_TOP / BM + E_NUM)   // 72

typedef _Float16 half8 __attribute__((ext_vector_type(8)));
typedef float f32x4 __attribute__((ext_vector_type(4)));

__device__ __forceinline__ unsigned short f2h(float f) {
  _Float16 h = (_Float16)f;
  return __builtin_bit_cast(unsigned short, h);
}

__device__ __forceinline__ half8 ld8(const unsigned short* p) {
  uint4 r = *(const uint4*)p;
  return __builtin_bit_cast(half8, r);
}

// ---------------- init: reset counters, mark all rows invalid ----------------
__global__ void init_meta(int* __restrict__ row2token, int* __restrict__ counts,
                          int* __restrict__ cursor, float* __restrict__ loadv) {
  int i = blockIdx.x * blockDim.x + threadIdx.x;
  if (i < PADROWS) row2token[i] = -1;
  if (i < E_NUM) { counts[i] = 0; cursor[i] = 0; loadv[i] = 0.f; }
}

// ---------------- router: one wave per token ----------------
__global__ __launch_bounds__(256) void router_kernel(
    const float* __restrict__ x, const float* __restrict__ gw,
    int* __restrict__ t2e, float* __restrict__ t2w,
    int* __restrict__ counts, float* __restrict__ loadv) {
  const int wave = threadIdx.x >> 6;
  const int lane = threadIdx.x & 63;
  const int t = blockIdx.x * 4 + wave;
  const float* xr = x + (size_t)t * H_DIM;
  float lg[E_NUM];
#pragma unroll
  for (int e = 0; e < E_NUM; e++) lg[e] = 0.f;
  for (int i = lane; i < H_DIM; i += 64) {
    float xv = xr[i];
    float4 g0 = *(const float4*)(gw + (size_t)i * E_NUM);
    float4 g1 = *(const float4*)(gw + (size_t)i * E_NUM + 4);
    lg[0] += xv * g0.x; lg[1] += xv * g0.y; lg[2] += xv * g0.z; lg[3] += xv * g0.w;
    lg[4] += xv * g1.x; lg[5] += xv * g1.y; lg[6] += xv * g1.z; lg[7] += xv * g1.w;
  }
#pragma unroll
  for (int e = 0; e < E_NUM; e++) {
    float v = lg[e];
#pragma unroll
    for (int off = 32; off > 0; off >>= 1) v += __shfl_down(v, off);
    lg[e] = v;
  }
  if (lane == 0) {
    float m = lg[0];
#pragma unroll
    for (int e = 1; e < E_NUM; e++) m = fmaxf(m, lg[e]);
    float p[E_NUM]; float s = 0.f;
#pragma unroll
    for (int e = 0; e < E_NUM; e++) { p[e] = __expf(lg[e] - m); s += p[e]; }
    int e1 = 0; float b1 = p[0];
#pragma unroll
    for (int e = 1; e < E_NUM; e++) if (p[e] > b1) { b1 = p[e]; e1 = e; }
    int e2 = -1; float b2 = -1.f;
#pragma unroll
    for (int e = 0; e < E_NUM; e++) if (e != e1 && p[e] > b2) { b2 = p[e]; e2 = e; }
    float rw1 = b1 / s, rw2 = b2 / s;       // softmax probs of the two selected
    float inv = 1.f / (rw1 + rw2);
    t2e[2 * t] = e1; t2e[2 * t + 1] = e2;
    t2w[2 * t] = rw1 * inv; t2w[2 * t + 1] = rw2 * inv;
    atomicAdd(&counts[e1], 1); atomicAdd(&counts[e2], 1);
    atomicAdd(&loadv[e1], rw1); atomicAdd(&loadv[e2], rw2);
  }
}

// ---------------- scan: padded offsets, M-block table, aux loss ----------------
__global__ void scan_build(const int* __restrict__ counts, const float* __restrict__ loadv,
                           int* __restrict__ poff, int* __restrict__ blk_e,
                           int* __restrict__ blk_r0, int* __restrict__ nblocks,
                           float* __restrict__ aux_out) {
  if (threadIdx.x != 0) return;
  int nb = 0, off = 0;
  for (int e = 0; e < E_NUM; e++) {
    poff[e] = off;
    int c = counts[e];
    int mb = (c + BM - 1) / BM;
    for (int j = 0; j < mb; j++) { blk_e[nb] = e; blk_r0[nb] = off + j * BM; nb++; }
    off += mb * BM;
  }
  *nblocks = nb;
  float aux = 0.f;
  for (int e = 0; e < E_NUM; e++)
    aux += (loadv[e] / (float)T_TOK) * ((float)counts[e] / (float)(T_TOK * K_TOP));
  aux_out[0] = aux * (float)E_NUM * AUX_COEF;
}

// ---------------- assign: token -> padded row slots ----------------
__global__ void assign_rows(const int* __restrict__ t2e, const float* __restrict__ t2w,
                            const int* __restrict__ poff, int* __restrict__ cursor,
                            int* __restrict__ row2token, float* __restrict__ row_w) {
  int t = blockIdx.x * blockDim.x + threadIdx.x;
  if (t >= T_TOK) return;
#pragma unroll
  for (int k = 0; k < K_TOP; k++) {
    int e = t2e[2 * t + k];
    int pos = poff[e] + atomicAdd(&cursor[e], 1);
    row2token[pos] = t;
    row_w[pos] = t2w[2 * t + k];
  }
}

// ---------------- gate/up GEMM + SwiGLU -> hdn (fp16) ----------------
__global__ __launch_bounds__(256) void gateup_kernel(
    const float* __restrict__ x, const float* __restrict__ wg, const float* __restrict__ wu,
    const int* __restrict__ row2token, const int* __restrict__ blk_e,
    const int* __restrict__ blk_r0, const int* __restrict__ nblocks,
    unsigned short* __restrict__ hdn) {
  const int bx = blockIdx.x;
  if (bx >= *nblocks) return;
  const int e = blk_e[bx];
  const int row0 = blk_r0[bx];
  const int n0 = blockIdx.y * BN;

  __shared__ unsigned short A[BM][LDK];
  __shared__ unsigned short Bg[BN][LDK];
  __shared__ unsigned short Bu[BN][LDK];

  const int tid = threadIdx.x;
  // A staging: 2 threads per row, 16 fp32 each
  const int ar = tid >> 1;
  const int ac = (tid & 1) * 16;
  const int tokA = row2token[row0 + ar];
  const float* xA = x + (size_t)(tokA < 0 ? 0 : tokA) * H_DIM + ac;
  // B staging: k = tid>>3 (0..31), 8 cols starting at (tid&7)*8
  const int bk = tid >> 3;
  const int bn = (tid & 7) * 8;
  const float* wge = wg + (size_t)e * H_DIM * I_DIM + (size_t)bk * I_DIM + n0 + bn;
  const float* wue = wu + (size_t)e * H_DIM * I_DIM + (size_t)bk * I_DIM + n0 + bn;

  const int w = tid >> 6, lane = tid & 63, q = lane >> 4, lm = lane & 15;

  f32x4 accg[2][4], accu[2][4];
  const f32x4 zv = {0.f, 0.f, 0.f, 0.f};
#pragma unroll
  for (int mi = 0; mi < 2; mi++)
#pragma unroll
    for (int ni = 0; ni < 4; ni++) { accg[mi][ni] = zv; accu[mi][ni] = zv; }

  for (int kt = 0; kt < H_DIM; kt += BK) {
    // stage A (fp32 gather -> fp16 LDS)
    {
      ushort4 h0, h1, h2, h3;
      if (tokA >= 0) {
        const float* p = xA + kt;
        float4 v0 = *(const float4*)(p + 0);
        float4 v1 = *(const float4*)(p + 4);
        float4 v2 = *(const float4*)(p + 8);
        float4 v3 = *(const float4*)(p + 12);
        h0 = make_ushort4(f2h(v0.x), f2h(v0.y), f2h(v0.z), f2h(v0.w));
        h1 = make_ushort4(f2h(v1.x), f2h(v1.y), f2h(v1.z), f2h(v1.w));
        h2 = make_ushort4(f2h(v2.x), f2h(v2.y), f2h(v2.z), f2h(v2.w));
        h3 = make_ushort4(f2h(v3.x), f2h(v3.y), f2h(v3.z), f2h(v3.w));
      } else {
        h0 = h1 = h2 = h3 = make_ushort4(0, 0, 0, 0);
      }
      *(ushort4*)&A[ar][ac + 0] = h0;
      *(ushort4*)&A[ar][ac + 4] = h1;
      *(ushort4*)&A[ar][ac + 8] = h2;
      *(ushort4*)&A[ar][ac + 12] = h3;
    }
    // stage Bg/Bu transposed (fp32 -> fp16)
    {
      const float* pg = wge + (size_t)kt * I_DIM;
      float4 g0 = *(const float4*)(pg + 0);
      float4 g1 = *(const float4*)(pg + 4);
      Bg[bn + 0][bk] = f2h(g0.x); Bg[bn + 1][bk] = f2h(g0.y);
      Bg[bn + 2][bk] = f2h(g0.z); Bg[bn + 3][bk] = f2h(g0.w);
      Bg[bn + 4][bk] = f2h(g1.x); Bg[bn + 5][bk] = f2h(g1.y);
      Bg[bn + 6][bk] = f2h(g1.z); Bg[bn + 7][bk] = f2h(g1.w);
      const float* pu = wue + (size_t)kt * I_DIM;
      float4 u0 = *(const float4*)(pu + 0);
      float4 u1 = *(const float4*)(pu + 4);
      Bu[bn + 0][bk] = f2h(u0.x); Bu[bn + 1][bk] = f2h(u0.y);
      Bu[bn + 2][bk] = f2h(u0.z); Bu[bn + 3][bk] = f2h(u0.w);
      Bu[bn + 4][bk] = f2h(u1.x); Bu[bn + 5][bk] = f2h(u1.y);
      Bu[bn + 6][bk] = f2h(u1.z); Bu[bn + 7][bk] = f2h(u1.w);
    }
    __syncthreads();
    half8 a0 = ld8(&A[w * 32 + 0 + lm][q * 8]);
    half8 a1 = ld8(&A[w * 32 + 16 + lm][q * 8]);
#pragma unroll
    for (int ni = 0; ni < 4; ni++) {
      half8 bgf = ld8(&Bg[ni * 16 + lm][q * 8]);
      half8 buf = ld8(&Bu[ni * 16 + lm][q * 8]);
      accg[0][ni] = __builtin_amdgcn_mfma_f32_16x16x32_f16(a0, bgf, accg[0][ni], 0, 0, 0);
      accg[1][ni] = __builtin_amdgcn_mfma_f32_16x16x32_f16(a1, bgf, accg[1][ni], 0, 0, 0);
      accu[0][ni] = __builtin_amdgcn_mfma_f32_16x16x32_f16(a0, buf, accu[0][ni], 0, 0, 0);
      accu[1][ni] = __builtin_amdgcn_mfma_f32_16x16x32_f16(a1, buf, accu[1][ni], 0, 0, 0);
    }
    __syncthreads();
  }
  // epilogue: hdn = silu(g) * u, fp16
#pragma unroll
  for (int mi = 0; mi < 2; mi++) {
#pragma unroll
    for (int ni = 0; ni < 4; ni++) {
#pragma unroll
      for (int r = 0; r < 4; r++) {
        int row = row0 + w * 32 + mi * 16 + q * 4 + r;
        int col = n0 + ni * 16 + lm;
        float g = accg[mi][ni][r];
        float u = accu[mi][ni][r];
        float hv = (g / (1.f + __expf(-g))) * u;
        hdn[(size_t)row * I_DIM + col] = f2h(hv);
      }
    }
  }
}

// ---------------- down GEMM + weighted scatter-add ----------------
__global__ __launch_bounds__(256) void down_kernel(
    const unsigned short* __restrict__ hdn, const float* __restrict__ wd,
    const int* __restrict__ row2token, const float* __restrict__ row_w,
    const int* __restrict__ blk_e, const int* __restrict__ blk_r0,
    const int* __restrict__ nblocks, float* __restrict__ out) {
  const int bx = blockIdx.x;
  if (bx >= *nblocks) return;
  const int e = blk_e[bx];
  const int row0 = blk_r0[bx];
  const int n0 = blockIdx.y * BN;

  __shared__ unsigned short A[BM][LDK];
  __shared__ unsigned short Bt[BN][LDK];

  const int tid = threadIdx.x;
  const int ar = tid >> 1;
  const int ac = (tid & 1) * 16;
  const unsigned short* hA = hdn + (size_t)(row0 + ar) * I_DIM + ac;
  const int bk = tid >> 3;
  const int bn = (tid & 7) * 8;
  const float* wde = wd + (size_t)e * I_DIM * H_DIM + (size_t)bk * H_DIM + n0 + bn;

  const int w = tid >> 6, lane = tid & 63, q = lane >> 4, lm = lane & 15;

  f32x4 acc[2][4];
  const f32x4 zv = {0.f, 0.f, 0.f, 0.f};
#pragma unroll
  for (int mi = 0; mi < 2; mi++)
#pragma unroll
    for (int ni = 0; ni < 4; ni++) acc[mi][ni] = zv;

  for (int kt = 0; kt < I_DIM; kt += BK) {
    // stage A (already fp16)
    {
      const uint4* p = (const uint4*)(hA + kt);
      *(uint4*)&A[ar][ac + 0] = p[0];
      *(uint4*)&A[ar][ac + 8] = p[1];
    }
    // stage B transposed
    {
      const float* pd = wde + (size_t)kt * H_DIM;
      float4 d0 = *(const float4*)(pd + 0);
      float4 d1 = *(const float4*)(pd + 4);
      Bt[bn + 0][bk] = f2h(d0.x); Bt[bn + 1][bk] = f2h(d0.y);
      Bt[bn + 2][bk] = f2h(d0.z); Bt[bn + 3][bk] = f2h(d0.w);
      Bt[bn + 4][bk] = f2h(d1.x); Bt[bn + 5][bk] = f2h(d1.y);
      Bt[bn + 6][bk] = f2h(d1.z); Bt[bn + 7][bk] = f2h(d1.w);
    }
    __syncthreads();
    half8 a0 = ld8(&A[w * 32 + 0 + lm][q * 8]);
    half8 a1 = ld8(&A[w * 32 + 16 + lm][q * 8]);
#pragma unroll
    for (int ni = 0; ni < 4; ni++) {
      half8 bf = ld8(&Bt[ni * 16 + lm][q * 8]);
      acc[0][ni] = __builtin_amdgcn_mfma_f32_16x16x32_f16(a0, bf, acc[0][ni], 0, 0, 0);
      acc[1][ni] = __builtin_amdgcn_mfma_f32_16x16x32_f16(a1, bf, acc[1][ni], 0, 0, 0);
    }
    __syncthreads();
  }
  // epilogue: scale by combine weight, scatter-add into out
#pragma unroll
  for (int mi = 0; mi < 2; mi++) {
#pragma unroll
    for (int r = 0; r < 4; r++) {
      int grow = row0 + w * 32 + mi * 16 + q * 4 + r;
      int tok = row2token[grow];
      if (tok < 0) continue;
      float rw = row_w[grow];
#pragma unroll
      for (int ni = 0; ni < 4; ni++) {
        float v = acc[mi][ni][r] * rw;
        atomicAdd(&out[(size_t)tok * H_DIM + n0 + ni * 16 + lm], v);
      }
    }
  }
}

extern "C" void kernel_launch(void* const* d_in, const int* in_sizes, int n_in,
                              void* d_out, int out_size, void* d_ws, size_t ws_size,
                              hipStream_t stream) {
  const float* x = (const float*)d_in[0];
  const float* gw = (const float*)d_in[1];
  const float* wg = (const float*)d_in[2];
  const float* wu = (const float*)d_in[3];
  const float* wd = (const float*)d_in[4];
  float* out = (float*)d_out;

  char* ws = (char*)d_ws;
  size_t o = 0;
  unsigned short* hdn = (unsigned short*)(ws + o); o += (size_t)PADROWS * I_DIM * 2;
  int* row2token = (int*)(ws + o); o += (size_t)PADROWS * 4;
  float* row_w = (float*)(ws + o); o += (size_t)PADROWS * 4;
  int* t2e = (int*)(ws + o); o += (size_t)T_TOK * 2 * 4;
  float* t2w = (float*)(ws + o); o += (size_t)T_TOK * 2 * 4;
  int* counts = (int*)(ws + o); o += E_NUM * 4;
  int* cursor = (int*)(ws + o); o += E_NUM * 4;
  float* loadv = (float*)(ws + o); o += E_NUM * 4;
  int* poff = (int*)(ws + o); o += E_NUM * 4;
  int* nblocks = (int*)(ws + o); o += 4;
  int* blk_e = (int*)(ws + o); o += MAXMB * 4;
  int* blk_r0 = (int*)(ws + o); o += MAXMB * 4;

  hipMemsetAsync(d_out, 0, (size_t)out_size * sizeof(float), stream);
  init_meta<<<(PADROWS + 255) / 256, 256, 0, stream>>>(row2token, counts, cursor, loadv);
  router_kernel<<<T_TOK / 4, 256, 0, stream>>>(x, gw, t2e, t2w, counts, loadv);
  scan_build<<<1, 64, 0, stream>>>(counts, loadv, poff, blk_e, blk_r0, nblocks,
                                   out + (size_t)T_TOK * H_DIM);
  assign_rows<<<T_TOK / 256, 256, 0, stream>>>(t2e, t2w, poff, cursor, row2token, row_w);
  gateup_kernel<<<dim3(MAXMB, I_DIM / BN), 256, 0, stream>>>(x, wg, wu, row2token, blk_e,
                                                             blk_r0, nblocks, hdn);
  down_kernel<<<dim3(MAXMB, H_DIM / BN), 256, 0, stream>>>(hdn, wd, row2token, row_w,
                                                           blk_e, blk_r0, nblocks, out);
}

// Round 2
// 950.709 us; speedup vs baseline: 1.3061x; 1.3061x over previous
//
#include <hip/hip_runtime.h>
#include <hip/hip_fp16.h>

#define T_TOK 4096
#define H_DIM 1024
#define I_DIM 4096
#define E_NUM 8
#define K_TOP 2
#define AUX_COEF 0.001f

#define BM 128
#define BN 64
#define PADROWS (T_TOK * K_TOP + E_NUM * BM) // 9216
#define MAXMB (T_TOK * K_TOP / BM + E_NUM)   // 72
#define LDT 72                               // convert-kernel LDS pitch (ushorts)

typedef _Float16 half8 __attribute__((ext_vector_type(8)));
typedef float f32x4 __attribute__((ext_vector_type(4)));
typedef unsigned short us8 __attribute__((ext_vector_type(8)));

__device__ __forceinline__ unsigned short f2h(float f) {
  _Float16 h = (_Float16)f;
  return __builtin_bit_cast(unsigned short, h);
}

__device__ __forceinline__ half8 ld8(const unsigned short* p) {
  uint4 r = *(const uint4*)p;
  return __builtin_bit_cast(half8, r);
}

// async global(16B/lane) -> LDS (wave-uniform base + lane*16)
__device__ __forceinline__ void async_cp16(const unsigned short* g, unsigned short* l) {
  __builtin_amdgcn_global_load_lds((const __attribute__((address_space(1))) unsigned int*)g,
                                   (__attribute__((address_space(3))) unsigned int*)l,
                                   16, 0, 0);
}

// ---------------- init ----------------
__global__ void init_meta(int* __restrict__ row2token, int* __restrict__ counts,
                          int* __restrict__ cursor, float* __restrict__ loadv) {
  int i = blockIdx.x * blockDim.x + threadIdx.x;
  if (i < PADROWS) row2token[i] = -1;
  if (i < E_NUM) { counts[i] = 0; cursor[i] = 0; loadv[i] = 0.f; }
}

// ---------------- router: one wave per token ----------------
__global__ __launch_bounds__(256) void router_kernel(
    const float* __restrict__ x, const float* __restrict__ gw,
    int* __restrict__ t2e, float* __restrict__ t2w,
    int* __restrict__ counts, float* __restrict__ loadv) {
  const int wave = threadIdx.x >> 6;
  const int lane = threadIdx.x & 63;
  const int t = blockIdx.x * 4 + wave;
  const float* xr = x + (size_t)t * H_DIM;
  float lg[E_NUM];
#pragma unroll
  for (int e = 0; e < E_NUM; e++) lg[e] = 0.f;
  for (int i = lane; i < H_DIM; i += 64) {
    float xv = xr[i];
    float4 g0 = *(const float4*)(gw + (size_t)i * E_NUM);
    float4 g1 = *(const float4*)(gw + (size_t)i * E_NUM + 4);
    lg[0] += xv * g0.x; lg[1] += xv * g0.y; lg[2] += xv * g0.z; lg[3] += xv * g0.w;
    lg[4] += xv * g1.x; lg[5] += xv * g1.y; lg[6] += xv * g1.z; lg[7] += xv * g1.w;
  }
#pragma unroll
  for (int e = 0; e < E_NUM; e++) {
    float v = lg[e];
#pragma unroll
    for (int off = 32; off > 0; off >>= 1) v += __shfl_down(v, off);
    lg[e] = v;
  }
  if (lane == 0) {
    float m = lg[0];
#pragma unroll
    for (int e = 1; e < E_NUM; e++) m = fmaxf(m, lg[e]);
    float p[E_NUM]; float s = 0.f;
#pragma unroll
    for (int e = 0; e < E_NUM; e++) { p[e] = __expf(lg[e] - m); s += p[e]; }
    int e1 = 0; float b1 = p[0];
#pragma unroll
    for (int e = 1; e < E_NUM; e++) if (p[e] > b1) { b1 = p[e]; e1 = e; }
    int e2 = -1; float b2 = -1.f;
#pragma unroll
    for (int e = 0; e < E_NUM; e++) if (e != e1 && p[e] > b2) { b2 = p[e]; e2 = e; }
    float rw1 = b1 / s, rw2 = b2 / s;
    float inv = 1.f / (rw1 + rw2);
    t2e[2 * t] = e1; t2e[2 * t + 1] = e2;
    t2w[2 * t] = rw1 * inv; t2w[2 * t + 1] = rw2 * inv;
    atomicAdd(&counts[e1], 1); atomicAdd(&counts[e2], 1);
    atomicAdd(&loadv[e1], rw1); atomicAdd(&loadv[e2], rw2);
  }
}

// ---------------- scan ----------------
__global__ void scan_build(const int* __restrict__ counts, const float* __restrict__ loadv,
                           int* __restrict__ poff, int* __restrict__ blk_e,
                           int* __restrict__ blk_r0, int* __restrict__ nblocks,
                           float* __restrict__ aux_out) {
  if (threadIdx.x != 0) return;
  int nb = 0, off = 0;
  for (int e = 0; e < E_NUM; e++) {
    poff[e] = off;
    int c = counts[e];
    int mb = (c + BM - 1) / BM;
    for (int j = 0; j < mb; j++) { blk_e[nb] = e; blk_r0[nb] = off + j * BM; nb++; }
    off += mb * BM;
  }
  *nblocks = nb;
  float aux = 0.f;
  for (int e = 0; e < E_NUM; e++)
    aux += (loadv[e] / (float)T_TOK) * ((float)counts[e] / (float)(T_TOK * K_TOP));
  aux_out[0] = aux * (float)E_NUM * AUX_COEF;
}

// ---------------- assign ----------------
__global__ void assign_rows(const int* __restrict__ t2e, const float* __restrict__ t2w,
                            const int* __restrict__ poff, int* __restrict__ cursor,
                            int* __restrict__ row2token, float* __restrict__ row_w) {
  int t = blockIdx.x * blockDim.x + threadIdx.x;
  if (t >= T_TOK) return;
#pragma unroll
  for (int k = 0; k < K_TOP; k++) {
    int e = t2e[2 * t + k];
    int pos = poff[e] + atomicAdd(&cursor[e], 1);
    row2token[pos] = t;
    row_w[pos] = t2w[2 * t + k];
  }
}

// ---------------- gather x rows -> xg fp16 [PADROWS][H] ----------------
__global__ __launch_bounds__(128) void gather_x(const float* __restrict__ x,
                                                const int* __restrict__ row2token,
                                                unsigned short* __restrict__ xg) {
  const int r = blockIdx.x;
  const int t = threadIdx.x;
  const int tok = row2token[r];
  us8 h;
  if (tok < 0) {
    h = (us8)0;
  } else {
    const float* p = x + (size_t)tok * H_DIM + t * 8;
    float4 v0 = *(const float4*)(p + 0);
    float4 v1 = *(const float4*)(p + 4);
    h[0] = f2h(v0.x); h[1] = f2h(v0.y); h[2] = f2h(v0.z); h[3] = f2h(v0.w);
    h[4] = f2h(v1.x); h[5] = f2h(v1.y); h[6] = f2h(v1.z); h[7] = f2h(v1.w);
  }
  *(us8*)(xg + (size_t)r * H_DIM + t * 8) = h;
}

// ---------------- transpose + fp32->fp16 convert: src[e][K][N] -> dst[e][N][K] ----------------
__global__ __launch_bounds__(256) void transpose_cvt(const float* __restrict__ src,
                                                     unsigned short* __restrict__ dst,
                                                     int K, int N) {
  __shared__ unsigned short S[64][LDT];
  const int k0 = blockIdx.x * 64;
  const int n0 = blockIdx.y * 64;
  const int e = blockIdx.z;
  const int t = threadIdx.x;
  // phase 1: coalesced global read (16 floats along N per thread), vector LDS write
  {
    const int kl = t >> 2;
    const int nc = (t & 3) << 4;
    const float* p = src + ((size_t)e * K + k0 + kl) * N + n0 + nc;
    float4 v0 = *(const float4*)(p + 0);
    float4 v1 = *(const float4*)(p + 4);
    float4 v2 = *(const float4*)(p + 8);
    float4 v3 = *(const float4*)(p + 12);
    us8 h0, h1;
    h0[0] = f2h(v0.x); h0[1] = f2h(v0.y); h0[2] = f2h(v0.z); h0[3] = f2h(v0.w);
    h0[4] = f2h(v1.x); h0[5] = f2h(v1.y); h0[6] = f2h(v1.z); h0[7] = f2h(v1.w);
    h1[0] = f2h(v2.x); h1[1] = f2h(v2.y); h1[2] = f2h(v2.z); h1[3] = f2h(v2.w);
    h1[4] = f2h(v3.x); h1[5] = f2h(v3.y); h1[6] = f2h(v3.z); h1[7] = f2h(v3.w);
    *(us8*)&S[kl][nc] = h0;
    *(us8*)&S[kl][nc + 8] = h1;
  }
  __syncthreads();
  // phase 2: strided LDS read (16 k for fixed n), coalesced global write
  {
    const int nl = t >> 2;
    const int kc = (t & 3) << 4;
    us8 o0, o1;
#pragma unroll
    for (int j = 0; j < 8; j++) o0[j] = S[kc + j][nl];
#pragma unroll
    for (int j = 0; j < 8; j++) o1[j] = S[kc + 8 + j][nl];
    unsigned short* q = dst + ((size_t)e * N + n0 + nl) * K + k0 + kc;
    *(us8*)(q + 0) = o0;
    *(us8*)(q + 8) = o1;
  }
}

// ---------------- gate/up GEMM + SwiGLU -> hdn fp16 ----------------
// A = xg [PADROWS][H], B = wgT/wuT [E][I][H] (k-contiguous). BK=64 as 2 halves of 32.
__global__ __launch_bounds__(256, 2) void gateup_kernel(
    const unsigned short* __restrict__ xg,
    const unsigned short* __restrict__ wgT, const unsigned short* __restrict__ wuT,
    const int* __restrict__ blk_e, const int* __restrict__ blk_r0,
    const int* __restrict__ nblocks, unsigned short* __restrict__ hdn) {
  const int bx = blockIdx.x;
  if (bx >= *nblocks) return;
  const int e = blk_e[bx];
  const int row0 = blk_r0[bx];
  const int n0 = blockIdx.y * BN;

  __shared__ unsigned short As[2][BM][32];   // 16 KB
  __shared__ unsigned short Bgs[2][BN][32];  // 8 KB
  __shared__ unsigned short Bus[2][BN][32];  // 8 KB

  const int tid = threadIdx.x;
  const int w = tid >> 6, lane = tid & 63, q = lane >> 4, lm = lane & 15;
  const int wm = w >> 1, wn = w & 1;
  const int l4 = lane >> 2, lg = lane & 3;

  const unsigned short* Ag = xg + (size_t)row0 * H_DIM;
  const unsigned short* Bgg = wgT + ((size_t)e * I_DIM + n0) * H_DIM;
  const unsigned short* Bug = wuT + ((size_t)e * I_DIM + n0) * H_DIM;

  f32x4 accg[4][2], accu[4][2];
  const f32x4 zv = {0.f, 0.f, 0.f, 0.f};
#pragma unroll
  for (int mi = 0; mi < 4; mi++)
#pragma unroll
    for (int ni = 0; ni < 2; ni++) { accg[mi][ni] = zv; accu[mi][ni] = zv; }

  for (int kt = 0; kt < H_DIM; kt += 64) {
    // stage A: 16 x 1KB issues (2 kk-halves x 8 row-groups of 16)
#pragma unroll
    for (int j = w; j < 16; j += 4) {
      int kk = j >> 3, ii = j & 7;
      async_cp16(Ag + (size_t)(ii * 16 + l4) * H_DIM + kt + kk * 32 + lg * 8,
                 &As[kk][ii * 16][0]);
    }
    // stage Bg/Bu: 8 issues each
#pragma unroll
    for (int j = w; j < 8; j += 4) {
      int kk = j >> 2, ii = j & 3;
      size_t go = (size_t)(ii * 16 + l4) * H_DIM + kt + kk * 32 + lg * 8;
      async_cp16(Bgg + go, &Bgs[kk][ii * 16][0]);
      async_cp16(Bug + go, &Bus[kk][ii * 16][0]);
    }
    __syncthreads();
#pragma unroll
    for (int kk = 0; kk < 2; kk++) {
      half8 a[4];
#pragma unroll
      for (int mi = 0; mi < 4; mi++)
        a[mi] = ld8(&As[kk][wm * 64 + mi * 16 + lm][q * 8]);
      half8 bg0 = ld8(&Bgs[kk][wn * 32 + lm][q * 8]);
      half8 bg1 = ld8(&Bgs[kk][wn * 32 + 16 + lm][q * 8]);
      half8 bu0 = ld8(&Bus[kk][wn * 32 + lm][q * 8]);
      half8 bu1 = ld8(&Bus[kk][wn * 32 + 16 + lm][q * 8]);
#pragma unroll
      for (int mi = 0; mi < 4; mi++) {
        accg[mi][0] = __builtin_amdgcn_mfma_f32_16x16x32_f16(a[mi], bg0, accg[mi][0], 0, 0, 0);
        accg[mi][1] = __builtin_amdgcn_mfma_f32_16x16x32_f16(a[mi], bg1, accg[mi][1], 0, 0, 0);
        accu[mi][0] = __builtin_amdgcn_mfma_f32_16x16x32_f16(a[mi], bu0, accu[mi][0], 0, 0, 0);
        accu[mi][1] = __builtin_amdgcn_mfma_f32_16x16x32_f16(a[mi], bu1, accu[mi][1], 0, 0, 0);
      }
    }
    __syncthreads();
  }
  // epilogue: silu(g)*u -> hdn fp16
#pragma unroll
  for (int mi = 0; mi < 4; mi++) {
#pragma unroll
    for (int ni = 0; ni < 2; ni++) {
#pragma unroll
      for (int r = 0; r < 4; r++) {
        int m = wm * 64 + mi * 16 + q * 4 + r;
        int col = n0 + wn * 32 + ni * 16 + lm;
        float g = accg[mi][ni][r];
        float u = accu[mi][ni][r];
        float hv = (g / (1.f + __expf(-g))) * u;
        hdn[(size_t)(row0 + m) * I_DIM + col] = f2h(hv);
      }
    }
  }
}

// ---------------- down GEMM + weighted scatter-add ----------------
// A = hdn [PADROWS][I], B = wdT [E][H][I] (k-contiguous).
__global__ __launch_bounds__(256, 2) void down_kernel(
    const unsigned short* __restrict__ hdn, const unsigned short* __restrict__ wdT,
    const int* __restrict__ row2token, const float* __restrict__ row_w,
    const int* __restrict__ blk_e, const int* __restrict__ blk_r0,
    const int* __restrict__ nblocks, float* __restrict__ out) {
  const int bx = blockIdx.x;
  if (bx >= *nblocks) return;
  const int e = blk_e[bx];
  const int row0 = blk_r0[bx];
  const int n0 = blockIdx.y * BN;

  __shared__ unsigned short As[2][BM][32];  // 16 KB
  __shared__ unsigned short Bs[2][BN][32];  // 8 KB

  const int tid = threadIdx.x;
  const int w = tid >> 6, lane = tid & 63, q = lane >> 4, lm = lane & 15;
  const int wm = w >> 1, wn = w & 1;
  const int l4 = lane >> 2, lg = lane & 3;

  const unsigned short* Ag = hdn + (size_t)row0 * I_DIM;
  const unsigned short* Bg = wdT + ((size_t)e * H_DIM + n0) * I_DIM;

  f32x4 acc[4][2];
  const f32x4 zv = {0.f, 0.f, 0.f, 0.f};
#pragma unroll
  for (int mi = 0; mi < 4; mi++)
#pragma unroll
    for (int ni = 0; ni < 2; ni++) acc[mi][ni] = zv;

  for (int kt = 0; kt < I_DIM; kt += 64) {
#pragma unroll
    for (int j = w; j < 16; j += 4) {
      int kk = j >> 3, ii = j & 7;
      async_cp16(Ag + (size_t)(ii * 16 + l4) * I_DIM + kt + kk * 32 + lg * 8,
                 &As[kk][ii * 16][0]);
    }
#pragma unroll
    for (int j = w; j < 8; j += 4) {
      int kk = j >> 2, ii = j & 3;
      async_cp16(Bg + (size_t)(ii * 16 + l4) * I_DIM + kt + kk * 32 + lg * 8,
                 &Bs[kk][ii * 16][0]);
    }
    __syncthreads();
#pragma unroll
    for (int kk = 0; kk < 2; kk++) {
      half8 a[4];
#pragma unroll
      for (int mi = 0; mi < 4; mi++)
        a[mi] = ld8(&As[kk][wm * 64 + mi * 16 + lm][q * 8]);
      half8 b0 = ld8(&Bs[kk][wn * 32 + lm][q * 8]);
      half8 b1 = ld8(&Bs[kk][wn * 32 + 16 + lm][q * 8]);
#pragma unroll
      for (int mi = 0; mi < 4; mi++) {
        acc[mi][0] = __builtin_amdgcn_mfma_f32_16x16x32_f16(a[mi], b0, acc[mi][0], 0, 0, 0);
        acc[mi][1] = __builtin_amdgcn_mfma_f32_16x16x32_f16(a[mi], b1, acc[mi][1], 0, 0, 0);
      }
    }
    __syncthreads();
  }
#pragma unroll
  for (int mi = 0; mi < 4; mi++) {
#pragma unroll
    for (int r = 0; r < 4; r++) {
      int grow = row0 + wm * 64 + mi * 16 + q * 4 + r;
      int tok = row2token[grow];
      if (tok < 0) continue;
      float rw = row_w[grow];
#pragma unroll
      for (int ni = 0; ni < 2; ni++) {
        float v = acc[mi][ni][r] * rw;
        atomicAdd(&out[(size_t)tok * H_DIM + n0 + wn * 32 + ni * 16 + lm], v);
      }
    }
  }
}

extern "C" void kernel_launch(void* const* d_in, const int* in_sizes, int n_in,
                              void* d_out, int out_size, void* d_ws, size_t ws_size,
                              hipStream_t stream) {
  const float* x = (const float*)d_in[0];
  const float* gw = (const float*)d_in[1];
  const float* wg = (const float*)d_in[2];
  const float* wu = (const float*)d_in[3];
  const float* wd = (const float*)d_in[4];
  float* out = (float*)d_out;

  char* ws = (char*)d_ws;
  size_t o = 0;
  unsigned short* wgT = (unsigned short*)(ws + o); o += (size_t)E_NUM * H_DIM * I_DIM * 2;
  unsigned short* wuT = (unsigned short*)(ws + o); o += (size_t)E_NUM * H_DIM * I_DIM * 2;
  unsigned short* wdT = (unsigned short*)(ws + o); o += (size_t)E_NUM * H_DIM * I_DIM * 2;
  unsigned short* xg = (unsigned short*)(ws + o); o += (size_t)PADROWS * H_DIM * 2;
  unsigned short* hdn = (unsigned short*)(ws + o); o += (size_t)PADROWS * I_DIM * 2;
  int* row2token = (int*)(ws + o); o += (size_t)PADROWS * 4;
  float* row_w = (float*)(ws + o); o += (size_t)PADROWS * 4;
  int* t2e = (int*)(ws + o); o += (size_t)T_TOK * 2 * 4;
  float* t2w = (float*)(ws + o); o += (size_t)T_TOK * 2 * 4;
  int* counts = (int*)(ws + o); o += E_NUM * 4;
  int* cursor = (int*)(ws + o); o += E_NUM * 4;
  float* loadv = (float*)(ws + o); o += E_NUM * 4;
  int* poff = (int*)(ws + o); o += E_NUM * 4;
  int* nblocks = (int*)(ws + o); o += 4;
  int* blk_e = (int*)(ws + o); o += MAXMB * 4;
  int* blk_r0 = (int*)(ws + o); o += MAXMB * 4;

  hipMemsetAsync(d_out, 0, (size_t)out_size * sizeof(float), stream);
  init_meta<<<(PADROWS + 255) / 256, 256, 0, stream>>>(row2token, counts, cursor, loadv);
  router_kernel<<<T_TOK / 4, 256, 0, stream>>>(x, gw, t2e, t2w, counts, loadv);
  scan_build<<<1, 64, 0, stream>>>(counts, loadv, poff, blk_e, blk_r0, nblocks,
                                   out + (size_t)T_TOK * H_DIM);
  assign_rows<<<T_TOK / 256, 256, 0, stream>>>(t2e, t2w, poff, cursor, row2token, row_w);
  gather_x<<<PADROWS, 128, 0, stream>>>(x, row2token, xg);
  transpose_cvt<<<dim3(H_DIM / 64, I_DIM / 64, E_NUM), 256, 0, stream>>>(wg, wgT, H_DIM, I_DIM);
  transpose_cvt<<<dim3(H_DIM / 64, I_DIM / 64, E_NUM), 256, 0, stream>>>(wu, wuT, H_DIM, I_DIM);
  transpose_cvt<<<dim3(I_DIM / 64, H_DIM / 64, E_NUM), 256, 0, stream>>>(wd, wdT, I_DIM, H_DIM);
  gateup_kernel<<<dim3(MAXMB, I_DIM / BN), 256, 0, stream>>>(xg, wgT, wuT, blk_e, blk_r0,
                                                             nblocks, hdn);
  down_kernel<<<dim3(MAXMB, H_DIM / BN), 256, 0, stream>>>(hdn, wdT, row2token, row_w,
                                                           blk_e, blk_r0, nblocks, out);
}